// Round 6
// baseline (5988.131 us; speedup 1.0000x reference)
//
#include <hip/hip_runtime.h>
#include <hip/hip_cooperative_groups.h>

namespace cg = cooperative_groups;

#define DEV __device__ __forceinline__

typedef _Float16 f16;
typedef __attribute__((ext_vector_type(8))) _Float16 f16x8;
typedef __attribute__((ext_vector_type(4))) float f32x4;

DEV int imin(int a, int b) { return a < b ? a : b; }

// LDS tile byte-swizzle: rows are 128B (64 f16); XOR row&7 into bits 4..6
DEV int swz(int row, int colByte) { return (row * 128 + colByte) ^ ((row & 7) << 4); }

// fp32 -> f16 hi/lo pair (hi RTZ via v_cvt_pkrtz, residual exact, lo RTZ)
DEV void split2(float x, float y, unsigned& hi, unsigned& lo) {
  auto h = __builtin_amdgcn_cvt_pkrtz(x, y);
  auto l = __builtin_amdgcn_cvt_pkrtz(x - (float)h[0], y - (float)h[1]);
  hi = __builtin_bit_cast(unsigned, h);
  lo = __builtin_bit_cast(unsigned, l);
}
DEV void split4(const float4& n, uint2& hi, uint2& lo) {
  split2(n.x, n.y, hi.x, lo.x);
  split2(n.z, n.w, hi.y, lo.y);
}

struct TI {
  const char* A; const char* AL; int ldaB;   // pair planes (bytes/row) or f32 base
  const float* B; int ldb;                   // f32 [K][N]
  const int* perm; int M;
  int m0, n0, sEnd;
  float* o32; int ldo;                       // CM1 resid-out / CM2 slab
  const float* hin;                          // CM1 residual source
  f16 *oh, *ol;                              // CM0 pair out
};

// AM: 0=f16 pair [M][K]; 1=f32 [M][K] (split at commit); 2=f16 pair + perm gather
// CM: 0=relu -> pair (guarded); 1=f32 out = acc + hin; 2=f32 slab (guarded)
// K fixed = 768 (12 steps of TK=64). 4 waves (2x2). Block = 256 threads.
template<int TM, int TN, int AM, int CM>
DEV void tileG(char* lds, const TI& t, int tid) {
  constexpr int WTM = TM / 2, WTN = TN / 2;
  constexpr int FM = WTM / 16, FN = WTN / 16;
  constexpr bool PAIR = (AM != 1);
  constexpr int UA = PAIR ? TM / 32 : TM / 16;
  constexpr int UB = TN / 16;
  const int lane = tid & 63;
  const int wr = tid >> 7, wc = (tid >> 6) & 1;
  char* As  = lds;
  char* AsL = lds + TM * 256;
  char* Bs  = lds + TM * 512;
  char* BsL = lds + TM * 512 + TN * 256;

  int arow[UA];
  #pragma unroll
  for (int u = 0; u < UA; ++u) {
    int id = tid + u * 256;
    int r = PAIR ? (id >> 3) : (id >> 4);
    int gr = imin(t.m0 + r, t.M - 1);
    arow[u] = (AM == 2) ? t.perm[gr] : gr;
  }

  int4 ah[2][PAIR ? UA : 1], al[2][PAIR ? UA : 1];
  float4 af[2][PAIR ? 1 : UA];
  float4 bf[2][UB];

  auto issueA = [&](int sl, int k0) {
    #pragma unroll
    for (int u = 0; u < UA; ++u) {
      int id = tid + u * 256;
      if constexpr (PAIR) {
        int kq = id & 7;
        long o = (long)arow[u] * t.ldaB + (long)(k0 + kq * 8) * 2;
        ah[sl][u] = *(const int4*)(t.A + o);
        al[sl][u] = *(const int4*)(t.AL + o);
      } else {
        int kq = id & 15;
        af[sl][u] = *(const float4*)(t.A + (long)arow[u] * t.ldaB + (long)(k0 + kq * 4) * 4);
      }
    }
  };
  auto issueB = [&](int sl, int k0) {
    #pragma unroll
    for (int u = 0; u < UB; ++u) {
      int id = tid + u * 256;
      int n = id % TN, kq = id / TN;
      const float* g = t.B + (long)(k0 + kq * 4) * t.ldb + t.n0 + n;
      float4 v;
      v.x = g[0]; v.y = g[t.ldb]; v.z = g[2 * (long)t.ldb]; v.w = g[3 * (long)t.ldb];
      bf[sl][u] = v;
    }
  };
  auto commitAB = [&](int sl, int bi) {
    char* ba = As + bi * TM * 128; char* baL = AsL + bi * TM * 128;
    #pragma unroll
    for (int u = 0; u < UA; ++u) {
      int id = tid + u * 256;
      if constexpr (PAIR) {
        int m = id >> 3, kq = id & 7;
        *(int4*)(ba + swz(m, kq * 16)) = ah[sl][u];
        *(int4*)(baL + swz(m, kq * 16)) = al[sl][u];
      } else {
        int m = id >> 4, kq = id & 15;
        uint2 h, l; split4(af[sl][u], h, l);
        *(uint2*)(ba + swz(m, kq * 8)) = h;
        *(uint2*)(baL + swz(m, kq * 8)) = l;
      }
    }
    char* bb = Bs + bi * TN * 128; char* bbL = BsL + bi * TN * 128;
    #pragma unroll
    for (int u = 0; u < UB; ++u) {
      int id = tid + u * 256;
      int n = id % TN, kq = id / TN;
      uint2 h, l; split4(bf[sl][u], h, l);
      *(uint2*)(bb + swz(n, kq * 8)) = h;
      *(uint2*)(bbL + swz(n, kq * 8)) = l;
    }
  };

  f32x4 acc[FM][FN] = {};
  auto compute = [&](int bi) {
    const char* pA = As + bi * TM * 128; const char* pAL = AsL + bi * TM * 128;
    const char* pB = Bs + bi * TN * 128; const char* pBL = BsL + bi * TN * 128;
    #pragma unroll
    for (int kk = 0; kk < 2; ++kk) {
      const int col2 = (kk * 32 + (lane >> 4) * 8) * 2;
      f16x8 xh[FM], xl[FM], yh[FN], yl[FN];
      #pragma unroll
      for (int i = 0; i < FM; ++i) {
        int r = wr * WTM + i * 16 + (lane & 15);
        xh[i] = *(const f16x8*)(pA + swz(r, col2));
        xl[i] = *(const f16x8*)(pAL + swz(r, col2));
      }
      #pragma unroll
      for (int j = 0; j < FN; ++j) {
        int r = wc * WTN + j * 16 + (lane & 15);
        yh[j] = *(const f16x8*)(pB + swz(r, col2));
        yl[j] = *(const f16x8*)(pBL + swz(r, col2));
      }
      #pragma unroll
      for (int i = 0; i < FM; ++i)
        #pragma unroll
        for (int j = 0; j < FN; ++j) {
          f32x4 c = acc[i][j];
          c = __builtin_amdgcn_mfma_f32_16x16x32_f16(xl[i], yh[j], c, 0, 0, 0);
          c = __builtin_amdgcn_mfma_f32_16x16x32_f16(xh[i], yl[j], c, 0, 0, 0);
          c = __builtin_amdgcn_mfma_f32_16x16x32_f16(xh[i], yh[j], c, 0, 0, 0);
          acc[i][j] = c;
        }
    }
  };

  __syncthreads();                 // previous tile's LDS readers are done
  issueA(0, 0); issueB(0, 0);
  #pragma unroll
  for (int s = 0; s < 12; ++s) {   // full unroll -> static reg-set indices
    commitAB(s & 1, s & 1);
    if (s < 11) { issueA((s + 1) & 1, (s + 1) * 64); issueB((s + 1) & 1, (s + 1) * 64); }
    __syncthreads();
    compute(s & 1);
  }

  const int cr = (lane >> 4) * 4, cc = lane & 15;
  #pragma unroll
  for (int i = 0; i < FM; ++i) {
    #pragma unroll
    for (int r = 0; r < 4; ++r) {
      int gm = t.m0 + wr * WTM + i * 16 + cr + r;
      if constexpr (CM == 0 || CM == 2) { if (gm >= t.sEnd || gm >= t.M) continue; }
      #pragma unroll
      for (int j = 0; j < FN; ++j) {
        int gn = t.n0 + wc * WTN + j * 16 + cc;
        float v = acc[i][j][r];
        if constexpr (CM == 0) {
          v = fmaxf(v, 0.f);
          f16 hv = (f16)v;
          t.oh[(long)gm * t.ldo + gn] = hv;
          t.ol[(long)gm * t.ldo + gn] = (f16)(v - (float)hv);
        } else if constexpr (CM == 1) {
          t.o32[(long)gm * t.ldo + gn] = v + t.hin[(long)gm * t.ldo + gn];
        } else {
          t.o32[(long)gm * t.ldo + gn] = v;
        }
      }
    }
  }
}

// fin: sum NS slabs (+prob/bias/resid) -> h f32 (WRH) + rmsnorm'd f16 pair; optional router
template<int NS, bool PERM, bool PROB, bool RESID, bool BIAS, bool WRH, bool ROUTER>
DEV void finRow(const float* src, long sst, const int* perm, const float* probIn,
                const float* Hin, const float* bias, float* Hout, const float* lnw,
                f16* nH, f16* nL, const float* rwl, int* eid, float* probOut,
                int s, int lane) {
  const int row = PERM ? perm[s] : s;
  const float p = PROB ? probIn[row] : 1.f;
  float4 v[3];
  float ss = 0.f;
  #pragma unroll
  for (int j = 0; j < 3; ++j) {
    const int c = j * 256 + lane * 4;
    float4 tv = *(const float4*)(src + (long)s * 768 + c);
    if constexpr (NS == 4) {
      float4 t1 = *(const float4*)(src + sst + (long)s * 768 + c);
      float4 t2 = *(const float4*)(src + 2 * sst + (long)s * 768 + c);
      float4 t3 = *(const float4*)(src + 3 * sst + (long)s * 768 + c);
      tv.x = (tv.x + t1.x) + (t2.x + t3.x); tv.y = (tv.y + t1.y) + (t2.y + t3.y);
      tv.z = (tv.z + t1.z) + (t2.z + t3.z); tv.w = (tv.w + t1.w) + (t2.w + t3.w);
    }
    if constexpr (PROB) { tv.x *= p; tv.y *= p; tv.z *= p; tv.w *= p; }
    if constexpr (BIAS) {
      float4 b = *(const float4*)(bias + c);
      tv.x += b.x; tv.y += b.y; tv.z += b.z; tv.w += b.w;
    }
    if constexpr (RESID) {
      float4 h = *(const float4*)(Hin + (long)row * 768 + c);
      tv.x += h.x; tv.y += h.y; tv.z += h.z; tv.w += h.w;
    }
    v[j] = tv;
    ss += tv.x * tv.x + tv.y * tv.y + tv.z * tv.z + tv.w * tv.w;
  }
  #pragma unroll
  for (int m = 1; m < 64; m <<= 1) ss += __shfl_xor(ss, m);
  const float rr = rsqrtf(ss * (1.f / 768.f) + 1e-6f);
  float le[8] = {0, 0, 0, 0, 0, 0, 0, 0};
  #pragma unroll
  for (int j = 0; j < 3; ++j) {
    const int c = j * 256 + lane * 4;
    if constexpr (WRH) *(float4*)(Hout + (long)row * 768 + c) = v[j];
    float4 w = *(const float4*)(lnw + c);
    float4 n;
    n.x = v[j].x * rr * w.x; n.y = v[j].y * rr * w.y;
    n.z = v[j].z * rr * w.z; n.w = v[j].w * rr * w.w;
    if constexpr (ROUTER) {
      const float* w0 = rwl + (long)c * 8;
      #pragma unroll
      for (int e = 0; e < 8; ++e) le[e] += n.x * w0[e];
      #pragma unroll
      for (int e = 0; e < 8; ++e) le[e] += n.y * w0[8 + e];
      #pragma unroll
      for (int e = 0; e < 8; ++e) le[e] += n.z * w0[16 + e];
      #pragma unroll
      for (int e = 0; e < 8; ++e) le[e] += n.w * w0[24 + e];
    }
    uint2 hi, lo;
    split4(n, hi, lo);
    *(uint2*)((char*)nH + ((long)row * 768 + c) * 2) = hi;
    *(uint2*)((char*)nL + ((long)row * 768 + c) * 2) = lo;
  }
  if constexpr (ROUTER) {
    #pragma unroll
    for (int m = 1; m < 64; m <<= 1) {
      #pragma unroll
      for (int e = 0; e < 8; ++e) le[e] += __shfl_xor(le[e], m);
    }
    if (lane == 0) {
      float mx = le[0]; int am = 0;
      #pragma unroll
      for (int e = 1; e < 8; ++e) if (le[e] > mx) { mx = le[e]; am = e; }
      float den = 0.f;
      #pragma unroll
      for (int e = 0; e < 8; ++e) den += expf(le[e] - mx);
      eid[row] = am; probOut[row] = 1.f / den;
    }
  }
}

DEV void fcRow(const f16* nH, const f16* nL, const float* fw, const float* fb,
               float* out, int row, int lane) {
  float acc[10] = {0, 0, 0, 0, 0, 0, 0, 0, 0, 0};
  #pragma unroll
  for (int i = 0; i < 12; ++i) {
    int k = i * 64 + lane;
    float n = (float)nH[(long)row * 768 + k] + (float)nL[(long)row * 768 + k];
    const float* w = fw + (long)k * 10;
    #pragma unroll
    for (int c = 0; c < 10; ++c) acc[c] += n * w[c];
  }
  #pragma unroll
  for (int m = 1; m < 64; m <<= 1) {
    #pragma unroll
    for (int c = 0; c < 10; ++c) acc[c] += __shfl_xor(acc[c], m);
  }
  if (lane == 0) {
    #pragma unroll
    for (int c = 0; c < 10; ++c) out[(long)row * 10 + c] = acc[c] + fb[c];
  }
}

struct MP {
  const float *x, *projw, *projb, *ln1, *wv, *wo, *ln2, *dwi, *dwo, *rw, *ewi, *ewo,
              *flnw, *fcw, *fcb;
  float *hA, *hB, *slab, *wct, *out, *prob;
  f16 *n1H, *n1L, *n2H, *n2L, *hidH, *hidL;
  int *eid, *perm, *off, *aux;
};

__global__ __launch_bounds__(256, 2) void mega(MP p) {
  __shared__ __align__(16) char lds[49152];
  __shared__ int scnt[8], sc2[8], soff[9];
  cg::grid_group grid = cg::this_grid();
  const int wg = blockIdx.x, nwg = gridDim.x, tid = threadIdx.x;
  const int lane = tid & 63, wid = tid >> 6;
  const long SST = 786432;

  // P0: wct[l][k][n] = wv[l] @ wo[l] (f32, fully coalesced)  +  proj split-K4 -> slab
  for (int t = wg; t < 4992; t += nwg) {
    TI ti{};
    if (t < 3456) {
      int l = t / 288, r = t % 288;
      ti.A = (const char*)(p.wv + (long)l * 589824); ti.ldaB = 3072;
      ti.B = p.wo + (long)l * 589824; ti.ldb = 768;
      ti.M = 768; ti.m0 = (r / 12) * 32; ti.n0 = (r % 12) * 64; ti.sEnd = 1 << 30;
      ti.o32 = p.wct + (long)l * 589824; ti.ldo = 768;
      tileG<32, 64, 1, 2>(lds, ti, tid);
    } else {
      int t2 = t - 3456; int kc = t2 / 384, r = t2 % 384;
      ti.A = (const char*)(p.x + (long)kc * 768); ti.ldaB = 12288;
      ti.B = p.projw + (long)kc * 589824; ti.ldb = 768;
      ti.M = 1024; ti.m0 = (r / 12) * 32; ti.n0 = (r % 12) * 64; ti.sEnd = 1 << 30;
      ti.o32 = p.slab + (long)kc * SST; ti.ldo = 768;
      tileG<32, 64, 1, 2>(lds, ti, tid);
    }
  }
  grid.sync();
  for (int s = wg * 4 + wid; s < 1024; s += nwg * 4)
    finRow<4, false, false, false, true, true, false>(p.slab, SST, nullptr, nullptr, nullptr,
        p.projb, p.hA, p.ln1, p.n1H, p.n1L, nullptr, nullptr, nullptr, s, lane);
  grid.sync();

  for (int l = 0; l < 12; ++l) {
    const int half = l >> 1;
    const float* lnNext = (l < 11) ? p.ln1 + (l + 1) * 768 : p.flnw;
    // attn: hB = hA + n1 @ wct[l]   (768 tiles 32x32)
    for (int t = wg; t < 768; t += nwg) {
      TI ti{};
      ti.A = (const char*)p.n1H; ti.AL = (const char*)p.n1L; ti.ldaB = 1536;
      ti.B = p.wct + (long)l * 589824; ti.ldb = 768;
      ti.M = 1024; ti.m0 = (t / 24) * 32; ti.n0 = (t % 24) * 32; ti.sEnd = 1 << 30;
      ti.o32 = p.hB; ti.ldo = 768; ti.hin = p.hA;
      tileG<32, 32, 0, 1>(lds, ti, tid);
    }
    grid.sync();
    // n2 = rmsnorm(hB, ln2[l]) (+ router on odd layers)
    if (l & 1) {
      for (int s = wg * 4 + wid; s < 1024; s += nwg * 4)
        finRow<1, false, false, false, false, false, true>(p.hB, 0, nullptr, nullptr, nullptr,
            nullptr, nullptr, p.ln2 + l * 768, p.n2H, p.n2L, p.rw + (long)half * 6144,
            p.eid, p.prob, s, lane);
    } else {
      for (int s = wg * 4 + wid; s < 1024; s += nwg * 4)
        finRow<1, false, false, false, false, false, false>(p.hB, 0, nullptr, nullptr, nullptr,
            nullptr, nullptr, p.ln2 + l * 768, p.n2H, p.n2L, nullptr, nullptr, nullptr, s, lane);
    }
    grid.sync();
    if (!(l & 1)) {
      for (int t = wg; t < 1536; t += nwg) {   // ffn1: hid = relu(n2 @ dwi) pair
        TI ti{};
        ti.A = (const char*)p.n2H; ti.AL = (const char*)p.n2L; ti.ldaB = 1536;
        ti.B = p.dwi + (long)half * 2359296; ti.ldb = 3072;
        ti.M = 1024; ti.m0 = (t / 96) * 64; ti.n0 = (t % 96) * 32; ti.sEnd = 1 << 30;
        ti.oh = p.hidH; ti.ol = p.hidL; ti.ldo = 3072;
        tileG<64, 32, 0, 0>(lds, ti, tid);
      }
      grid.sync();
      for (int t = wg; t < 1536; t += nwg) {   // ffn2 split-K4 -> slab
        int kc = t / 384, r = t % 384;
        TI ti{};
        ti.A = (const char*)p.hidH + (long)kc * 1536; ti.AL = (const char*)p.hidL + (long)kc * 1536;
        ti.ldaB = 6144;
        ti.B = p.dwo + (long)half * 2359296 + (long)kc * 589824; ti.ldb = 768;
        ti.M = 1024; ti.m0 = (r / 12) * 32; ti.n0 = (r % 12) * 64; ti.sEnd = 1 << 30;
        ti.o32 = p.slab + (long)kc * SST; ti.ldo = 768;
        tileG<32, 64, 0, 2>(lds, ti, tid);
      }
      grid.sync();
      for (int s = wg * 4 + wid; s < 1024; s += nwg * 4)
        finRow<4, false, false, true, false, true, false>(p.slab, SST, nullptr, nullptr, p.hB,
            nullptr, p.hA, lnNext, p.n1H, p.n1L, nullptr, nullptr, nullptr, s, lane);
      grid.sync();
    } else {
      if (wg == 0) {   // scan: counts, offsets, perm, tile-prefix tables
        if (tid < 8) { scnt[tid] = 0; sc2[tid] = 0; }
        __syncthreads();
        for (int t = tid; t < 1024; t += 256) atomicAdd(&scnt[p.eid[t]], 1);
        __syncthreads();
        if (tid == 0) {
          int acc = 0, a1 = 0, a2 = 0;
          for (int e = 0; e < 8; ++e) {
            soff[e] = acc; p.off[e] = acc;
            p.aux[e] = a1; p.aux[16 + e] = a2;
            a1 += (scnt[e] + 63) >> 6;
            a2 += (scnt[e] + 31) >> 5;
            acc += scnt[e];
          }
          p.off[8] = acc; p.aux[8] = a1; p.aux[24] = a2;
        }
        __syncthreads();
        for (int t = tid; t < 1024; t += 256) {
          int e = p.eid[t];
          int r = atomicAdd(&sc2[e], 1);
          p.perm[soff[e] + r] = t;
        }
      }
      grid.sync();
      int ofs[9], ty1[9], ty2[9];
      #pragma unroll
      for (int i = 0; i < 9; ++i) { ofs[i] = p.off[i]; ty1[i] = p.aux[i]; ty2[i] = p.aux[16 + i]; }
      for (int t = wg; t < ty1[8] * 96; t += nwg) {   // eg1: hid[slot] = relu(n2[perm] @ ewi[e])
        int xx = t % 96, q = t / 96;
        int e = 0;
        #pragma unroll
        for (int i = 1; i < 8; ++i) if (q >= ty1[i]) e = i;
        TI ti{};
        ti.A = (const char*)p.n2H; ti.AL = (const char*)p.n2L; ti.ldaB = 1536;
        ti.perm = p.perm;
        ti.B = p.ewi + (long)(half * 8 + e) * 2359296; ti.ldb = 3072;
        ti.M = 1024; ti.m0 = ofs[e] + (q - ty1[e]) * 64; ti.n0 = xx * 32; ti.sEnd = ofs[e + 1];
        ti.oh = p.hidH; ti.ol = p.hidL; ti.ldo = 3072;
        tileG<64, 32, 2, 0>(lds, ti, tid);
      }
      grid.sync();
      for (int t = wg; t < ty2[8] * 48; t += nwg) {   // eg2 split-K4 -> slab
        int xx = t % 12, r = t / 12, kc = r & 3, q = r >> 2;
        int e = 0;
        #pragma unroll
        for (int i = 1; i < 8; ++i) if (q >= ty2[i]) e = i;
        TI ti{};
        ti.A = (const char*)p.hidH + (long)kc * 1536; ti.AL = (const char*)p.hidL + (long)kc * 1536;
        ti.ldaB = 6144;
        ti.B = p.ewo + (long)(half * 8 + e) * 2359296 + (long)kc * 589824; ti.ldb = 768;
        ti.M = 1024; ti.m0 = ofs[e] + (q - ty2[e]) * 32; ti.n0 = xx * 64; ti.sEnd = ofs[e + 1];
        ti.o32 = p.slab + (long)kc * SST; ti.ldo = 768;
        tileG<32, 64, 0, 2>(lds, ti, tid);
      }
      grid.sync();
      for (int s = wg * 4 + wid; s < 1024; s += nwg * 4)
        finRow<4, true, true, true, false, true, false>(p.slab, SST, p.perm, p.prob, p.hB,
            nullptr, p.hA, lnNext, p.n1H, p.n1L, nullptr, nullptr, nullptr, s, lane);
      grid.sync();
    }
  }
  for (int s = wg * 4 + wid; s < 1024; s += nwg * 4)
    fcRow(p.n1H, p.n1L, p.fcw, p.fcb, p.out, s, lane);
}

extern "C" void kernel_launch(void* const* d_in, const int* in_sizes, int n_in,
                              void* d_out, int out_size, void* d_ws, size_t ws_size,
                              hipStream_t stream) {
  if (ws_size < 66072832u) return;
  char* ws = (char*)d_ws;
  MP h{};
  h.x     = (const float*)d_in[0];
  h.projw = (const float*)d_in[1];
  h.projb = (const float*)d_in[2];
  h.ln1   = (const float*)d_in[3];
  h.wv    = (const float*)d_in[4];
  h.wo    = (const float*)d_in[5];
  h.ln2   = (const float*)d_in[6];
  h.dwi   = (const float*)d_in[7];
  h.dwo   = (const float*)d_in[8];
  h.rw    = (const float*)d_in[9];
  h.ewi   = (const float*)d_in[10];
  h.ewo   = (const float*)d_in[11];
  h.flnw  = (const float*)d_in[12];
  h.fcw   = (const float*)d_in[13];
  h.fcb   = (const float*)d_in[14];
  h.hA   = (float*)(ws);
  h.hB   = (float*)(ws + 3145728);
  h.n1H  = (f16*)(ws + 6291456);
  h.n1L  = (f16*)(ws + 7864320);
  h.n2H  = (f16*)(ws + 9437184);
  h.n2L  = (f16*)(ws + 11010048);
  h.hidH = (f16*)(ws + 12582912);
  h.hidL = (f16*)(ws + 18874368);
  h.slab = (float*)(ws + 25165824);
  h.wct  = (float*)(ws + 37748736);
  h.eid  = (int*)(ws + 66060288);
  h.prob = (float*)(ws + 66064384);
  h.perm = (int*)(ws + 66068480);
  h.off  = (int*)(ws + 66072576);
  h.aux  = (int*)(ws + 66072704);
  h.out  = (float*)d_out;

  int nb = 0;
  if (hipOccupancyMaxActiveBlocksPerMultiprocessor(&nb, mega, 256, 0) != hipSuccess || nb < 1)
    nb = 1;
  int g = nb * 256;
  if (g > 768) g = 768;
  void* args[] = { &h };
  hipLaunchCooperativeKernel(mega, dim3(g), dim3(256), args, 0, stream);
}